// Round 5
// baseline (273.516 us; speedup 1.0000x reference)
//
#include <hip/hip_runtime.h>
#include <math.h>

// InnerSoftShiftTriple: b=8, c=512 (d=256), h=w=64, N=4096. Hole rows/cols [16,48).
// Round 5: R4 + XCD-affinity work queues. R3/R4 attn ran at L3 bandwidth (~7.6 TB/s
// on ~614 MB of re-reads) because the blockIdx%8->XCD guess evidently doesn't hold.
// Now each block reads its hardware XCC_ID and pops a (batch==xcc) work ticket from
// per-batch atomic queues (d_ws), guaranteeing the 3.5 MB/batch KnT/Fc/Qn set is
// re-read from the local L2. Partial-O writes stay non-temporal (keep L2 clean);
// bulk copies revert to regular stores.

typedef float  f32x16 __attribute__((ext_vector_type(16)));
typedef float  f32x4v __attribute__((ext_vector_type(4)));
typedef short  bf16x8 __attribute__((ext_vector_type(8)));
#define MFMA32(a, b, c) __builtin_amdgcn_mfma_f32_32x32x16_bf16(a, b, c, 0, 0, 0)

// out.latter region of batch b (1048576 floats) as shorts:
//   [0, 786432)        KnT_c [3072 keys][256 d]   normalized latter, compacted known
//   [786432, 1572864)  Fc    [256 d][3072 keys]   former bf16, compacted known
//   [1572864, 1835008) Qn    [1024 q][256 d]      normalized latter, hole positions
// ws (floats): [0,32768) rcpn ; [32768,49152) l partials ; [49152,49160) XCD queues

__device__ __forceinline__ unsigned short f2bf(float f) {
    union { float f; unsigned u; } v; v.f = f;
    unsigned u = v.u + 0x7fffu + ((v.u >> 16) & 1u);   // RNE
    return (unsigned short)(u >> 16);
}

__device__ __forceinline__ void nt_store4(float* p, float a, float b, float c, float d) {
    f32x4v v; v[0] = a; v[1] = b; v[2] = c; v[3] = d;
    __builtin_nontemporal_store(v, (f32x4v*)p);
}

__device__ __forceinline__ int get_xcc_id() {
    int x;
    asm volatile("s_getreg_b32 %0, hwreg(HW_REG_XCC_ID, 0, 4)" : "=s"(x));
    return x & 7;
}

// rcpn[b][n] = 1/(||latter[b,:,n]|| + 1e-8) -> ws[0..32768); also zero XCD queues.
__global__ void norm_kernel(const float* __restrict__ x, float* __restrict__ ws) {
    __shared__ float red[8][33];
    int blk = blockIdx.x;           // 1024 = b(8) x nc(128)
    int b = blk >> 7, nc = blk & 127;
    int t = threadIdx.x;
    if (blk == 0 && t < 8) ((int*)(ws + 49152))[t] = 0;
    int nl = t & 31, dg = t >> 5;
    const float* p = x + (size_t)(b * 512 + 256) * 4096 + nc * 32 + nl;
    float acc = 0.f;
    #pragma unroll 8
    for (int i = 0; i < 32; ++i) { float v = p[(size_t)(dg * 32 + i) * 4096]; acc += v * v; }
    red[dg][nl] = acc;
    __syncthreads();
    if (t < 32) {
        float s = 0.f;
        #pragma unroll
        for (int g = 0; g < 8; ++g) s += red[g][t];
        ws[b * 4096 + nc * 32 + t] = 1.0f / (sqrtf(s) + 1e-8f);
    }
}

// fused: blk<8192 -> former copy + Fc scratch; else KnT/Qn build
__global__ void build_kernel(const float* __restrict__ x, const float* __restrict__ ws,
                             float* __restrict__ out) {
    int blk = blockIdx.x;
    int t = threadIdx.x;
    if (blk < 8192) {
        int i4 = blk * 256 + t;
        int e = i4 << 2;
        int b = e >> 20, rem = e & 1048575;
        int d = rem >> 12, n = rem & 4095;
        float4 v = *(const float4*)(x + ((size_t)b << 21) + rem);
        *(float4*)(out + (size_t)b * 3145728 + rem) = v;
        int r = n >> 6, c = n & 63;
        bool hole = (r >= 16) && (r < 48) && (c >= 16) && (c < 48);
        if (!hole) {
            int ci;
            if (r < 16) ci = n;
            else if (r >= 48) ci = n - 1024;
            else ci = 1024 + (r - 16) * 32 + (c < 16 ? c : c - 32);
            unsigned short* fc = (unsigned short*)(out + (size_t)b * 3145728 + 1048576) + 786432;
            ushort4 hh; hh.x = f2bf(v.x); hh.y = f2bf(v.y); hh.z = f2bf(v.z); hh.w = f2bf(v.w);
            *(ushort4*)(fc + (size_t)d * 3072 + ci) = hh;
        }
    } else {
        __shared__ float tile[64 * 69];
        int blk2 = blk - 8192;           // 2048 = b(8) x dt(4) x nt(64)
        int b = blk2 >> 8, dt = (blk2 >> 6) & 3, nt = blk2 & 63;
        int d0 = dt << 6, n0 = nt << 6;
        const float* lat = x + (size_t)(b * 512 + 256) * 4096;
        const float* rb  = ws + b * 4096 + n0;
        #pragma unroll
        for (int i = 0; i < 4; ++i) {
            int cc = t + 256 * i;
            int dr = cc >> 4, nc = (cc & 15) << 2;
            float4 v = *(const float4*)(lat + (size_t)(d0 + dr) * 4096 + n0 + nc);
            float4 r = *(const float4*)(rb + nc);
            tile[dr * 69 + nc + 0] = v.x * r.x;
            tile[dr * 69 + nc + 1] = v.y * r.y;
            tile[dr * 69 + nc + 2] = v.z * r.z;
            tile[dr * 69 + nc + 3] = v.w * r.w;
        }
        __syncthreads();
        unsigned short* base16 = (unsigned short*)(out + (size_t)b * 3145728 + 1048576);
        #pragma unroll
        for (int i = 0; i < 2; ++i) {
            int cc = t + 256 * i;
            int nn = cc >> 3, dp = (cc & 7) << 3;
            int n = n0 + nn;
            int r = n >> 6, c = n & 63;
            bool hole = (r >= 16) && (r < 48) && (c >= 16) && (c < 48);
            unsigned short* dst;
            if (hole) {
                dst = base16 + 1572864 + (size_t)((r - 16) * 32 + (c - 16)) * 256 + d0 + dp;
            } else {
                int ci;
                if (r < 16) ci = n;
                else if (r >= 48) ci = n - 1024;
                else ci = 1024 + (r - 16) * 32 + (c < 16 ? c : c - 32);
                dst = base16 + (size_t)ci * 256 + d0 + dp;
            }
            ushort4 h0, h1;
            h0.x = f2bf(tile[(dp + 0) * 69 + nn]); h0.y = f2bf(tile[(dp + 1) * 69 + nn]);
            h0.z = f2bf(tile[(dp + 2) * 69 + nn]); h0.w = f2bf(tile[(dp + 3) * 69 + nn]);
            h1.x = f2bf(tile[(dp + 4) * 69 + nn]); h1.y = f2bf(tile[(dp + 5) * 69 + nn]);
            h1.z = f2bf(tile[(dp + 6) * 69 + nn]); h1.w = f2bf(tile[(dp + 7) * 69 + nn]);
            *(ushort4*)(dst)     = h0;
            *(ushort4*)(dst + 4) = h1;
        }
    }
}

// grid 512 (overprovisioned pool); work item = (batch==XCD, qt, h). 512 thr, 8 waves.
__launch_bounds__(512, 1)
__global__ void attn_kernel(float* __restrict__ out, float* __restrict__ ws) {
    __shared__ __align__(16) short pbuf[2][64 * 136];  // P [64 q][128 k] bf16, dbuf
    __shared__ float l_acc[64];
    __shared__ int s_item;

    const int tid = threadIdx.x;

    // claim a work item with XCD affinity: try own batch queue first, then steal
    if (tid == 0) {
        int* cnt = (int*)(ws + 49152);
        int xcc = get_xcc_id();
        int item = -1;
        for (int i = 0; i < 8; ++i) {
            int q = (xcc + i) & 7;
            int tk = atomicAdd(&cnt[q], 1);
            if (tk < 32) { item = q * 32 + tk; break; }
        }
        s_item = item;
    }
    __syncthreads();
    const int item = s_item;
    if (item < 0) return;                 // pool drained: all 256 items claimed

    const int b = item >> 5;
    const int qt = item & 15;
    const int h = (item >> 4) & 1;        // key half

    const int w = tid >> 6, lane = tid & 63;
    const int l32 = lane & 31, half = lane >> 5;
    const int qh = w & 1;                 // S-phase q-group
    const int ks = w >> 1;                // S-phase key slice (0..3)

    const unsigned short* base16 = (const unsigned short*)(out + (size_t)b * 3145728 + 1048576);
    const unsigned short* knt = base16;
    const unsigned short* fc  = base16 + 786432;
    const unsigned short* qn  = base16 + 1572864;

    if (tid < 64) l_acc[tid] = 0.f;

    // Q resident in registers: A-frags for 16 k-steps (d = j*16 + half*8 + 0..7)
    bf16x8 qf[16];
    {
        const unsigned short* qrow = qn + (size_t)(qt * 64 + qh * 32 + l32) * 256 + half * 8;
        #pragma unroll
        for (int j = 0; j < 16; ++j) qf[j] = *(const bf16x8*)(qrow + j * 16);
    }

    f32x16 oc0, oc1;
    float lp[16];
    #pragma unroll
    for (int r = 0; r < 16; ++r) { oc0[r] = 0.f; oc1[r] = 0.f; lp[r] = 0.f; }

    const int kb0 = h * 1536;

    // prefetch K jb0 frags for it=0
    bf16x8 kfp[8];
    {
        const unsigned short* kp = knt + (size_t)(kb0 + ks * 32 + l32) * 256 + half * 8;
        #pragma unroll
        for (int j = 0; j < 8; ++j) kfp[j] = *(const bf16x8*)(kp + j * 16);
    }

    for (int it = 0; it < 12; ++it) {
        const int kb = kb0 + (it << 7);
        const unsigned short* kp = knt + (size_t)(kb + ks * 32 + l32) * 256 + half * 8;
        // issue jb1 loads up front, run jb0 MFMAs on prefetched frags meanwhile
        bf16x8 kf1[8];
        #pragma unroll
        for (int j = 0; j < 8; ++j) kf1[j] = *(const bf16x8*)(kp + (8 + j) * 16);
        f32x16 sacc;
        #pragma unroll
        for (int r = 0; r < 16; ++r) sacc[r] = 0.f;
        #pragma unroll
        for (int j = 0; j < 8; ++j) sacc = MFMA32(qf[j], kfp[j], sacc);
        #pragma unroll
        for (int j = 0; j < 8; ++j) sacc = MFMA32(qf[8 + j], kf1[j], sacc);
        // p = exp(s-1) (scores are cosines <= 1: fixed max), pack to LDS
        short* pb = pbuf[it & 1];
        #pragma unroll
        for (int r = 0; r < 16; ++r) {
            float p = __expf(sacc[r] - 1.0f);
            lp[r] += p;
            int row = (r & 3) + 8 * (r >> 2) + 4 * half + qh * 32;
            pb[row * 136 + ks * 32 + l32] = (short)f2bf(p);
        }
        // F frags + next-iter K jb0 prefetch: both drained by the barrier's vmcnt wait
        bf16x8 ff[8];
        const unsigned short* fp = fc + (size_t)(w * 32 + l32) * 3072 + kb + half * 8;
        #pragma unroll
        for (int j = 0; j < 8; ++j) ff[j] = *(const bf16x8*)(fp + j * 16);
        if (it < 11) {
            const unsigned short* kpn = knt + (size_t)(kb + 128 + ks * 32 + l32) * 256 + half * 8;
            #pragma unroll
            for (int j = 0; j < 8; ++j) kfp[j] = *(const bf16x8*)(kpn + j * 16);
        }
        __syncthreads();
        // O += P . F (A from LDS, B in registers); wave owns 32 d-cols
        #pragma unroll
        for (int j = 0; j < 8; ++j) {
            bf16x8 a0 = *(const bf16x8*)(pb + l32 * 136        + j * 16 + half * 8);
            bf16x8 a1 = *(const bf16x8*)(pb + (l32 + 32) * 136 + j * 16 + half * 8);
            oc0 = MFMA32(a0, ff[j], oc0);
            oc1 = MFMA32(a1, ff[j], oc1);
        }
    }

    // row-sums l: reduce across 32 lanes of each half, then across ks waves
    #pragma unroll
    for (int r = 0; r < 16; ++r) {
        float v = lp[r];
        v += __shfl_xor(v, 1);  v += __shfl_xor(v, 2);  v += __shfl_xor(v, 4);
        v += __shfl_xor(v, 8);  v += __shfl_xor(v, 16);
        lp[r] = v;
    }
    if (l32 == 0) {
        #pragma unroll
        for (int r = 0; r < 16; ++r) {
            int row = (r & 3) + 8 * (r >> 2) + 4 * half + qh * 32;
            atomicAdd(&l_acc[row], lp[r]);
        }
    }
    __syncthreads();
    if (tid < 64) {
        ws[32768 + (((b * 16 + qt) << 1) + h) * 64 + tid] = l_acc[tid];
    }

    // store unnormalized partials NT (keep L2 clean): h=0 -> hole cols, h=1 -> scratch
    float* obase = out + (size_t)(b * 768 + 512) * 4096;
    const int d = w * 32 + l32;
    #pragma unroll
    for (int tile = 0; tile < 2; ++tile) {
        #pragma unroll
        for (int g = 0; g < 4; ++g) {
            int rowb = 8 * g + 4 * half;
            int n = (h == 0) ? ((16 + qt * 2 + tile) * 64 + 16 + rowb)
                             : (qt * 64 + tile * 32 + rowb);
            float* pdst = obase + (size_t)d * 4096 + n;
            if (tile == 0) nt_store4(pdst, oc0[4*g], oc0[4*g+1], oc0[4*g+2], oc0[4*g+3]);
            else           nt_store4(pdst, oc1[4*g], oc1[4*g+1], oc1[4*g+2], oc1[4*g+3]);
        }
    }
}

// fused: blk<512 -> combine (merge halves, divide by l, zero consumed scratch col);
//        else latter copy + zero non-hole shift cols with n>=1024.
__global__ void final_kernel(const float* __restrict__ x, float* __restrict__ out,
                             const float* __restrict__ ws) {
    int blk = blockIdx.x;
    int t = threadIdx.x;
    if (blk < 512) {
        int b = blk >> 6, qt = (blk >> 2) & 15, dg = blk & 3;   // 8 x 16 x 4
        const float* l0 = ws + 32768 + ((b * 16 + qt) << 1) * 64;
        const float* l1 = l0 + 64;
        int qq = t & 63, ds = t >> 6;
        float linv = 1.0f / (l0[qq] + l1[qq]);
        int tile = qq >> 5, row = qq & 31;
        int nf = (16 + qt * 2 + tile) * 64 + 16 + row;
        int ns = qt * 64 + qq;
        float* obase = out + (size_t)(b * 768 + 512) * 4096;
        #pragma unroll 4
        for (int i = 0; i < 16; ++i) {
            int d = dg * 64 + ds * 16 + i;
            float v0 = obase[(size_t)d * 4096 + nf];
            float v1 = obase[(size_t)d * 4096 + ns];
            __builtin_nontemporal_store((v0 + v1) * linv, obase + (size_t)d * 4096 + nf);
            __builtin_nontemporal_store(0.0f, obase + (size_t)d * 4096 + ns);
        }
    } else {
        int i4 = (blk - 512) * 256 + t;   // 4,194,304 float4s
        int e = i4 << 2;
        if (e < 8388608) {
            int b = e >> 20, rem = e & 1048575;
            const float* src = x + ((size_t)b << 21) + 1048576 + rem;
            float4 v = *(const float4*)src;
            *(float4*)(out + (size_t)b * 3145728 + 1048576 + rem) = v;
        } else {
            int e2 = e - 8388608;
            int b = e2 >> 20, rem = e2 & 1048575;
            int n = rem & 4095;
            if (n >= 1024) {              // n<1024 scratch cols are zeroed by combine
                int r = n >> 6, c = n & 63;
                bool hole = (r >= 16) && (r < 48) && (c >= 16) && (c < 48);
                if (!hole) nt_store4(out + (size_t)b * 3145728 + 2097152 + rem, 0.f, 0.f, 0.f, 0.f);
            }
        }
    }
}

extern "C" void kernel_launch(void* const* d_in, const int* in_sizes, int n_in,
                              void* d_out, int out_size, void* d_ws, size_t ws_size,
                              hipStream_t stream) {
    const float* x = (const float*)d_in[0];
    float* out = (float*)d_out;
    float* ws  = (float*)d_ws;

    hipLaunchKernelGGL(norm_kernel,  dim3(1024),  dim3(256), 0, stream, x, ws);
    hipLaunchKernelGGL(build_kernel, dim3(10240), dim3(256), 0, stream, x, ws, out);
    hipLaunchKernelGGL(attn_kernel,  dim3(512),   dim3(512), 0, stream, out, ws);
    hipLaunchKernelGGL(final_kernel, dim3(16896), dim3(256), 0, stream, x, out, ws);
}